// Round 4
// baseline (539.052 us; speedup 1.0000x reference)
//
#include <hip/hip_runtime.h>
#include <math.h>

#define BB 32
#define NN 1024
#define DD 256
#define KSTEP 32
#define LDK 40   // bf16 LDS row stride (shorts): 80B rows, uniform bank spread, 16B aligned
#define SLD 132  // f32 s-tile LDS row stride (floats): 16B aligned (4-way frag reads, ok)

typedef __attribute__((ext_vector_type(8))) short short8;
typedef __attribute__((ext_vector_type(8))) unsigned short u16x8;
typedef __attribute__((ext_vector_type(4))) float f32x4;

__device__ __forceinline__ unsigned short f2bf(float x) {  // round-nearest-even (split path)
  unsigned u = __float_as_uint(x);
  return (unsigned short)((u + 0x7fffu + ((u >> 16) & 1u)) >> 16);
}
__device__ __forceinline__ unsigned short f2bf_fast(float x) {  // round-half-up (P values)
  return (unsigned short)((__float_as_uint(x) + 0x8000u) >> 16);
}
__device__ __forceinline__ float bf2f(unsigned short h) {
  return __uint_as_float((unsigned)h << 16);
}

// ---------------------------------------------------------------------------
// k_split: f32 -> bf16 hi/lo, float4-vectorized.
// ---------------------------------------------------------------------------
__global__ __launch_bounds__(256) void k_split(const float* __restrict__ src,
                                               unsigned short* __restrict__ hi,
                                               unsigned short* __restrict__ lo, int n4) {
  int i = blockIdx.x * 256 + threadIdx.x;
  if (i >= n4) return;
  float4 v = ((const float4*)src)[i];
  float xs[4] = {v.x, v.y, v.z, v.w};
  ushort4 h4, l4;
  unsigned short* hp = (unsigned short*)&h4;
  unsigned short* lp = (unsigned short*)&l4;
  #pragma unroll
  for (int j = 0; j < 4; ++j) {
    unsigned short h = f2bf(xs[j]);
    hp[j] = h;
    lp[j] = f2bf(xs[j] - bf2f(h));
  }
  ((ushort4*)hi)[i] = h4;
  ((ushort4*)lo)[i] = l4;
}

// W [k][n] -> Wt [n][k], split hi/lo.
__global__ __launch_bounds__(256) void k_splitW(const float* __restrict__ W,
                                                unsigned short* __restrict__ Wth,
                                                unsigned short* __restrict__ Wtl) {
  int k = blockIdx.x, n = threadIdx.x;
  float x = W[k * DD + n];
  unsigned short h = f2bf(x);
  Wth[n * DD + k] = h;
  Wtl[n * DD + k] = f2bf(x - bf2f(h));
}

// ---------------------------------------------------------------------------
// k_transT: bf16 [BB*NN][DD] -> [BB][DD][NN]. LDS-free: strided reads are
// L1-amortized (one 128B line per (n, d-tile) serves 64 d-iterations),
// writes coalesced. Tile 64n x 64d.
// ---------------------------------------------------------------------------
__global__ __launch_bounds__(256) void k_transT(const unsigned short* __restrict__ in,
                                                unsigned short* __restrict__ out) {
  const int b = blockIdx.z;
  const int n0 = blockIdx.x * 64, d0 = blockIdx.y * 64;
  const int tid = threadIdx.x;
  const int nl = tid & 63, dc = tid >> 6;  // lane = n-offset, 4 d-chunks of 16
  #pragma unroll
  for (int dj = 0; dj < 16; ++dj) {
    int d = d0 + dc * 16 + dj;
    unsigned short v = in[((size_t)b * NN + n0 + nl) * DD + d];
    out[((size_t)b * DD + d) * NN + n0 + nl] = v;
  }
}

// ---------------------------------------------------------------------------
// k_gemm_nt<EPI>: C = A @ B^T, split-bf16 (3 MFMAs). 128x128 tile, 4 waves.
//   EPI 0 (tW): C -> bf16 hi/lo.
//   EPI 1 (s):  C -> f32 s, PLUS fused row/col (max,sumexp) tile partials.
// ---------------------------------------------------------------------------
template <int EPI>
__global__ __launch_bounds__(256) void k_gemm_nt(const unsigned short* __restrict__ Ahg,
                                                 const unsigned short* __restrict__ Alg,
                                                 const unsigned short* __restrict__ Bhg,
                                                 const unsigned short* __restrict__ Blg,
                                                 unsigned short* __restrict__ outh,
                                                 unsigned short* __restrict__ outl,
                                                 float* __restrict__ outf,
                                                 float2* __restrict__ prow,
                                                 float2* __restrict__ pcol, int b0) {
  size_t aoff = 0, boff = 0, coff = 0;
  int ldC = 256;
  const int g = blockIdx.z;
  if (EPI == 1) {
    int b = b0 + g;
    aoff = (size_t)b * NN * DD;
    boff = (size_t)b * NN * DD;
    coff = (size_t)g * NN * NN;
    ldC = NN;
  }
  const int n0 = blockIdx.x * 128, m0 = blockIdx.y * 128;
  __shared__ unsigned short Ah[128][LDK], Al[128][LDK], Bh[128][LDK], Bl[128][LDK];
  __shared__ float2 rowbuf[128][2];
  __shared__ float2 colbuf[128][2];
  const int tid = threadIdx.x;
  const int lane = tid & 63, w = tid >> 6;
  const int wr = (w >> 1) * 64, wc = (w & 1) * 64;
  const int sr = tid >> 1, sk = (tid & 1) * 16;

  f32x4 acc[4][4] = {};
  const int fr = lane & 15, fk = (lane >> 4) * 8;

  for (int k0 = 0; k0 < DD; k0 += KSTEP) {
    const size_t abase = aoff + (size_t)(n0 + sr) * DD + k0 + sk;
    const size_t bbase = boff + (size_t)(m0 + sr) * DD + k0 + sk;
    *(u16x8*)&Ah[sr][sk] = *(const u16x8*)&Ahg[abase];
    *(u16x8*)&Ah[sr][sk + 8] = *(const u16x8*)&Ahg[abase + 8];
    *(u16x8*)&Al[sr][sk] = *(const u16x8*)&Alg[abase];
    *(u16x8*)&Al[sr][sk + 8] = *(const u16x8*)&Alg[abase + 8];
    *(u16x8*)&Bh[sr][sk] = *(const u16x8*)&Bhg[bbase];
    *(u16x8*)&Bh[sr][sk + 8] = *(const u16x8*)&Bhg[bbase + 8];
    *(u16x8*)&Bl[sr][sk] = *(const u16x8*)&Blg[bbase];
    *(u16x8*)&Bl[sr][sk + 8] = *(const u16x8*)&Blg[bbase + 8];
    __syncthreads();
    short8 ah[4], al[4], bh[4], bl[4];
    #pragma unroll
    for (int mi = 0; mi < 4; ++mi) {
      ah[mi] = *(const short8*)&Ah[wr + mi * 16 + fr][fk];
      al[mi] = *(const short8*)&Al[wr + mi * 16 + fr][fk];
    }
    #pragma unroll
    for (int ni = 0; ni < 4; ++ni) {
      bh[ni] = *(const short8*)&Bh[wc + ni * 16 + fr][fk];
      bl[ni] = *(const short8*)&Bl[wc + ni * 16 + fr][fk];
    }
    #pragma unroll
    for (int mi = 0; mi < 4; ++mi)
      #pragma unroll
      for (int ni = 0; ni < 4; ++ni) {
        acc[mi][ni] = __builtin_amdgcn_mfma_f32_16x16x32_bf16(ah[mi], bh[ni], acc[mi][ni], 0, 0, 0);
        acc[mi][ni] = __builtin_amdgcn_mfma_f32_16x16x32_bf16(ah[mi], bl[ni], acc[mi][ni], 0, 0, 0);
        acc[mi][ni] = __builtin_amdgcn_mfma_f32_16x16x32_bf16(al[mi], bh[ni], acc[mi][ni], 0, 0, 0);
      }
    __syncthreads();
  }
  const int fq = (lane >> 4) * 4;
  // C write
  #pragma unroll
  for (int mi = 0; mi < 4; ++mi)
    #pragma unroll
    for (int ni = 0; ni < 4; ++ni)
      #pragma unroll
      for (int q = 0; q < 4; ++q) {
        int row = n0 + wr + mi * 16 + fq + q;
        int col = m0 + wc + ni * 16 + fr;
        float x = acc[mi][ni][q];
        if (EPI == 0) {
          unsigned short h = f2bf(x);
          outh[(size_t)row * 256 + col] = h;
          outl[(size_t)row * 256 + col] = f2bf(x - bf2f(h));
        } else {
          outf[coff + (size_t)row * ldC + col] = x;
        }
      }
  if (EPI == 1) {
    // ---- fused tile stats ----
    // ROW partials: per (mi,q) row, reduce over ni (in-thread) then fr lanes.
    #pragma unroll
    for (int mi = 0; mi < 4; ++mi)
      #pragma unroll
      for (int q = 0; q < 4; ++q) {
        float v0 = acc[mi][0][q], v1 = acc[mi][1][q], v2 = acc[mi][2][q], v3 = acc[mi][3][q];
        float mx = fmaxf(fmaxf(v0, v1), fmaxf(v2, v3));
        #pragma unroll
        for (int mask = 1; mask <= 8; mask <<= 1) mx = fmaxf(mx, __shfl_xor(mx, mask));
        float se = __expf(v0 - mx) + __expf(v1 - mx) + __expf(v2 - mx) + __expf(v3 - mx);
        #pragma unroll
        for (int mask = 1; mask <= 8; mask <<= 1) se += __shfl_xor(se, mask);
        if (fr == 0) rowbuf[wr + mi * 16 + fq + q][w & 1] = make_float2(mx, se);
      }
    // COL partials: per ni col, reduce over (mi,q) in-thread then g-groups.
    #pragma unroll
    for (int ni = 0; ni < 4; ++ni) {
      float mx = -INFINITY;
      #pragma unroll
      for (int mi = 0; mi < 4; ++mi)
        #pragma unroll
        for (int q = 0; q < 4; ++q) mx = fmaxf(mx, acc[mi][ni][q]);
      mx = fmaxf(mx, __shfl_xor(mx, 16));
      mx = fmaxf(mx, __shfl_xor(mx, 32));
      float se = 0.f;
      #pragma unroll
      for (int mi = 0; mi < 4; ++mi)
        #pragma unroll
        for (int q = 0; q < 4; ++q) se += __expf(acc[mi][ni][q] - mx);
      se += __shfl_xor(se, 16);
      se += __shfl_xor(se, 32);
      if ((lane >> 4) == 0) colbuf[wc + ni * 16 + fr][w >> 1] = make_float2(mx, se);
    }
    __syncthreads();
    if (tid < 128) {
      float2 a = rowbuf[tid][0], c = rowbuf[tid][1];
      float nm = fmaxf(a.x, c.x);
      float s = a.y * __expf(a.x - nm) + c.y * __expf(c.x - nm);
      prow[((size_t)g * NN + n0 + tid) * 8 + blockIdx.y] = make_float2(nm, s);
    } else {
      int m = tid - 128;
      float2 a = colbuf[m][0], c = colbuf[m][1];
      float nm = fmaxf(a.x, c.x);
      float s = a.y * __expf(a.x - nm) + c.y * __expf(c.x - nm);
      pcol[((size_t)g * NN + m0 + m) * 8 + blockIdx.x] = make_float2(nm, s);
    }
  }
}

// ---------------------------------------------------------------------------
// k_comb: merge 8 (max,sumexp) partials -> lse = max + log(sum).
// ---------------------------------------------------------------------------
__global__ __launch_bounds__(256) void k_comb(const float2* __restrict__ part,
                                              float* __restrict__ lse, int b0) {
  const int g = blockIdx.y, b = b0 + g;
  const int i = blockIdx.x * 256 + threadIdx.x;
  float mx = -INFINITY, sum = 0.f;
  #pragma unroll
  for (int c = 0; c < 8; ++c) {
    float2 p = part[((size_t)g * NN + i) * 8 + c];
    float nm = fmaxf(mx, p.x);
    sum = sum * __expf(mx - nm) + p.y * __expf(p.x - nm);
    mx = nm;
  }
  lse[(size_t)b * NN + i] = mx + __logf(sum);
}

// ---------------------------------------------------------------------------
// k_outg<MODE>: out[d][m] = sum_k AT[d][k] * exp(s[k][m] - L)
//   MODE 0 (t_out): AT=tT, L = lc[m] (per-lane); MODE 1 (f_out): AT=fT, L = lr[k].
// A: linear bf16 staging + ds_read_b128 frags. P: f32 s-tile in LDS, exp at
// frag build (in-register, no second LDS trip).
// ---------------------------------------------------------------------------
template <int MODE>
__global__ __launch_bounds__(256) void k_outg(const unsigned short* __restrict__ ATg,
                                              const float* __restrict__ s,
                                              const float* __restrict__ lse,
                                              float* __restrict__ out, int b0) {
  const int g = blockIdx.z, b = b0 + g;
  const int m0 = blockIdx.x * 128, d0 = blockIdx.y * 128;
  const unsigned short* A = ATg + (size_t)b * DD * NN;  // [d][k]
  const float* S = s + (size_t)g * NN * NN;             // [k][m]
  float* O = out + (size_t)b * DD * NN;                 // [d][m]
  __shared__ unsigned short Asm[128][LDK];
  __shared__ float Ssm[KSTEP][SLD];
  __shared__ float lrs[KSTEP];
  const int tid = threadIdx.x;
  const int lane = tid & 63, w = tid >> 6;
  const int wr = (w >> 1) * 64, wc = (w & 1) * 64;
  const int fr = lane & 15, fk = (lane >> 4) * 8;
  const int sr = tid >> 1, sk = (tid & 1) * 16;       // A staging
  const int skk = tid >> 3, smq = (tid & 7) * 16;     // S staging
  float lcv[4];
  if (MODE == 0) {
    #pragma unroll
    for (int ni = 0; ni < 4; ++ni)
      lcv[ni] = lse[(size_t)b * NN + m0 + wc + ni * 16 + fr];
  }
  f32x4 acc[4][4] = {};
  for (int k0 = 0; k0 < NN; k0 += KSTEP) {
    const size_t ab = (size_t)(d0 + sr) * NN + k0 + sk;
    *(u16x8*)&Asm[sr][sk] = *(const u16x8*)&A[ab];
    *(u16x8*)&Asm[sr][sk + 8] = *(const u16x8*)&A[ab + 8];
    #pragma unroll
    for (int i = 0; i < 4; ++i)
      *(float4*)&Ssm[skk][smq + 4 * i] =
          *(const float4*)&S[(size_t)(k0 + skk) * NN + m0 + smq + 4 * i];
    if (MODE == 1 && tid < KSTEP) lrs[tid] = lse[(size_t)b * NN + k0 + tid];
    __syncthreads();
    short8 af[4], bfr[4];
    #pragma unroll
    for (int mi = 0; mi < 4; ++mi) af[mi] = *(const short8*)&Asm[wr + mi * 16 + fr][fk];
    #pragma unroll
    for (int ni = 0; ni < 4; ++ni) {
      unsigned short tmp[8];
      #pragma unroll
      for (int j = 0; j < 8; ++j) {
        float x = Ssm[fk + j][wc + ni * 16 + fr];
        float L = (MODE == 0) ? lcv[ni] : lrs[fk + j];
        tmp[j] = f2bf_fast(__expf(x - L));
      }
      bfr[ni] = *(const short8*)tmp;
    }
    #pragma unroll
    for (int mi = 0; mi < 4; ++mi)
      #pragma unroll
      for (int ni = 0; ni < 4; ++ni)
        acc[mi][ni] = __builtin_amdgcn_mfma_f32_16x16x32_bf16(af[mi], bfr[ni], acc[mi][ni], 0, 0, 0);
    __syncthreads();
  }
  const int fq = (lane >> 4) * 4;
  #pragma unroll
  for (int mi = 0; mi < 4; ++mi)
    #pragma unroll
    for (int ni = 0; ni < 4; ++ni)
      #pragma unroll
      for (int q = 0; q < 4; ++q)
        O[(size_t)(d0 + wr + mi * 16 + fq + q) * NN + m0 + wc + ni * 16 + fr] = acc[mi][ni][q];
}

// ---------------------------------------------------------------------------
extern "C" void kernel_launch(void* const* d_in, const int* in_sizes, int n_in,
                              void* d_out, int out_size, void* d_ws, size_t ws_size,
                              hipStream_t stream) {
  const float* t = (const float*)d_in[0];
  const float* f = (const float*)d_in[1];
  const float* W = (const float*)d_in[2];
  float* out = (float*)d_out;

  const size_t NE = (size_t)BB * NN * DD;
  char* ws = (char*)d_ws;
  size_t off = 0;
  auto alloc = [&](size_t bytes) { char* p = ws + off; off += (bytes + 255) & ~(size_t)255; return p; };
  unsigned short* t_hi = (unsigned short*)alloc(NE * 2);
  unsigned short* t_lo = (unsigned short*)alloc(NE * 2);
  unsigned short* f_hi = (unsigned short*)alloc(NE * 2);
  unsigned short* f_lo = (unsigned short*)alloc(NE * 2);
  unsigned short* tw_hi = (unsigned short*)alloc(NE * 2);
  unsigned short* tw_lo = (unsigned short*)alloc(NE * 2);
  unsigned short* tT = (unsigned short*)alloc(NE * 2);
  unsigned short* fT = (unsigned short*)alloc(NE * 2);
  unsigned short* Wth = (unsigned short*)alloc((size_t)DD * DD * 2);
  unsigned short* Wtl = (unsigned short*)alloc((size_t)DD * DD * 2);
  float* lr = (float*)alloc((size_t)BB * NN * 4);
  float* lc = (float*)alloc((size_t)BB * NN * 4);
  float2* prow = (float2*)alloc((size_t)BB * NN * 8 * 8);
  float2* pcol = (float2*)alloc((size_t)BB * NN * 8 * 8);
  size_t fixed_bytes = off;
  size_t per_batch = (size_t)NN * NN * sizeof(float);
  int G = 1;
  if (ws_size > fixed_bytes + per_batch) {
    size_t avail = (ws_size - fixed_bytes) / per_batch;
    G = (int)(avail < BB ? avail : BB);
    if (G < 1) G = 1;
  }
  float* sbuf = (float*)(ws + fixed_bytes);

  float* out_t = out;
  float* out_f = out + (size_t)BB * DD * NN;

  // Prologue
  k_split<<<(int)((NE / 4 + 255) / 256), 256, 0, stream>>>(t, t_hi, t_lo, (int)(NE / 4));
  k_split<<<(int)((NE / 4 + 255) / 256), 256, 0, stream>>>(f, f_hi, f_lo, (int)(NE / 4));
  k_splitW<<<DD, DD, 0, stream>>>(W, Wth, Wtl);
  k_transT<<<dim3(NN / 64, DD / 64, BB), 256, 0, stream>>>(t_hi, tT);
  k_transT<<<dim3(NN / 64, DD / 64, BB), 256, 0, stream>>>(f_hi, fT);
  k_gemm_nt<0><<<dim3(256, 2, 1), 256, 0, stream>>>(t_hi, t_lo, Wth, Wtl, tw_hi, tw_lo,
                                                    nullptr, nullptr, nullptr, 0);

  for (int b0 = 0; b0 < BB; b0 += G) {
    int g = BB - b0 < G ? BB - b0 : G;
    k_gemm_nt<1><<<dim3(8, 8, g), 256, 0, stream>>>(tw_hi, tw_lo, f_hi, f_lo, nullptr, nullptr,
                                                    sbuf, prow, pcol, b0);
    k_comb<<<dim3(NN / 256, g), 256, 0, stream>>>(prow, lr, b0);
    k_comb<<<dim3(NN / 256, g), 256, 0, stream>>>(pcol, lc, b0);
    k_outg<0><<<dim3(8, 2, g), 256, 0, stream>>>(tT, sbuf, lc, out_t, b0);
    k_outg<1><<<dim3(8, 2, g), 256, 0, stream>>>(fT, sbuf, lr, out_f, b0);
  }
}

// Round 6
// 530.735 us; speedup vs baseline: 1.0157x; 1.0157x over previous
//
#include <hip/hip_runtime.h>
#include <math.h>

#define BB 32
#define NN 1024
#define DD 256
#define KSTEP 32
#define LDK 40   // bf16 LDS row stride (shorts): 80B rows, uniform bank tiling, 16B aligned

typedef __attribute__((ext_vector_type(8))) short short8;
typedef __attribute__((ext_vector_type(8))) unsigned short u16x8;
typedef __attribute__((ext_vector_type(4))) float f32x4;

__device__ __forceinline__ unsigned short f2bf(float x) {  // round-nearest-even (split path)
  unsigned u = __float_as_uint(x);
  return (unsigned short)((u + 0x7fffu + ((u >> 16) & 1u)) >> 16);
}
__device__ __forceinline__ unsigned short f2bf_fast(float x) {  // round-half-up (P values)
  return (unsigned short)((__float_as_uint(x) + 0x8000u) >> 16);
}
__device__ __forceinline__ float bf2f(unsigned short h) {
  return __uint_as_float((unsigned)h << 16);
}

// ---------------------------------------------------------------------------
// k_split: f32 -> bf16 hi/lo, float4-vectorized.
// ---------------------------------------------------------------------------
__global__ __launch_bounds__(256) void k_split(const float* __restrict__ src,
                                               unsigned short* __restrict__ hi,
                                               unsigned short* __restrict__ lo, int n4) {
  int i = blockIdx.x * 256 + threadIdx.x;
  if (i >= n4) return;
  float4 v = ((const float4*)src)[i];
  float xs[4] = {v.x, v.y, v.z, v.w};
  ushort4 h4, l4;
  unsigned short* hp = (unsigned short*)&h4;
  unsigned short* lp = (unsigned short*)&l4;
  #pragma unroll
  for (int j = 0; j < 4; ++j) {
    unsigned short h = f2bf(xs[j]);
    hp[j] = h;
    lp[j] = f2bf(xs[j] - bf2f(h));
  }
  ((ushort4*)hi)[i] = h4;
  ((ushort4*)lo)[i] = l4;
}

// W [k][n] -> Wt [n][k], split hi/lo.
__global__ __launch_bounds__(256) void k_splitW(const float* __restrict__ W,
                                                unsigned short* __restrict__ Wth,
                                                unsigned short* __restrict__ Wtl) {
  int k = blockIdx.x, n = threadIdx.x;
  float x = W[k * DD + n];
  unsigned short h = f2bf(x);
  Wth[n * DD + k] = h;
  Wtl[n * DD + k] = f2bf(x - bf2f(h));
}

// ---------------------------------------------------------------------------
// k_transT: bf16 [BB*NN][DD] -> [BB][DD][NN]. Strided reads L1-amortized,
// writes coalesced.
// ---------------------------------------------------------------------------
__global__ __launch_bounds__(256) void k_transT(const unsigned short* __restrict__ in,
                                                unsigned short* __restrict__ out) {
  const int b = blockIdx.z;
  const int n0 = blockIdx.x * 64, d0 = blockIdx.y * 64;
  const int tid = threadIdx.x;
  const int nl = tid & 63, dc = tid >> 6;
  #pragma unroll
  for (int dj = 0; dj < 16; ++dj) {
    int d = d0 + dc * 16 + dj;
    unsigned short v = in[((size_t)b * NN + n0 + nl) * DD + d];
    out[((size_t)b * DD + d) * NN + n0 + nl] = v;
  }
}

// ---------------------------------------------------------------------------
// k_gemm_nt<EPI>: C = A @ B^T, split-bf16 (3 MFMAs). 128x128 tile, 4 waves.
//   EPI 0 (tW): C -> bf16 hi/lo.
//   EPI 1 (s):  C -> f32 s, PLUS fused row/col (max,sumexp) tile partials
//               (stat buffers ALIAS the dead frag LDS -> LDS stays 40960).
// ---------------------------------------------------------------------------
template <int EPI>
__global__ __launch_bounds__(256) void k_gemm_nt(const unsigned short* __restrict__ Ahg,
                                                 const unsigned short* __restrict__ Alg,
                                                 const unsigned short* __restrict__ Bhg,
                                                 const unsigned short* __restrict__ Blg,
                                                 unsigned short* __restrict__ outh,
                                                 unsigned short* __restrict__ outl,
                                                 float* __restrict__ outf,
                                                 float2* __restrict__ prow,
                                                 float2* __restrict__ pcol, int b0) {
  size_t aoff = 0, boff = 0, coff = 0;
  int ldC = 256;
  const int g = blockIdx.z;
  if (EPI == 1) {
    int b = b0 + g;
    aoff = (size_t)b * NN * DD;
    boff = (size_t)b * NN * DD;
    coff = (size_t)g * NN * NN;
    ldC = NN;
  }
  const int n0 = blockIdx.x * 128, m0 = blockIdx.y * 128;
  __shared__ unsigned short Ah[128][LDK], Al[128][LDK], Bh[128][LDK], Bl[128][LDK];
  const int tid = threadIdx.x;
  const int lane = tid & 63, w = tid >> 6;
  const int wr = (w >> 1) * 64, wc = (w & 1) * 64;
  const int sr = tid >> 1, sk = (tid & 1) * 16;

  f32x4 acc[4][4] = {};
  const int fr = lane & 15, fk = (lane >> 4) * 8;

  for (int k0 = 0; k0 < DD; k0 += KSTEP) {
    const size_t abase = aoff + (size_t)(n0 + sr) * DD + k0 + sk;
    const size_t bbase = boff + (size_t)(m0 + sr) * DD + k0 + sk;
    *(u16x8*)&Ah[sr][sk] = *(const u16x8*)&Ahg[abase];
    *(u16x8*)&Ah[sr][sk + 8] = *(const u16x8*)&Ahg[abase + 8];
    *(u16x8*)&Al[sr][sk] = *(const u16x8*)&Alg[abase];
    *(u16x8*)&Al[sr][sk + 8] = *(const u16x8*)&Alg[abase + 8];
    *(u16x8*)&Bh[sr][sk] = *(const u16x8*)&Bhg[bbase];
    *(u16x8*)&Bh[sr][sk + 8] = *(const u16x8*)&Bhg[bbase + 8];
    *(u16x8*)&Bl[sr][sk] = *(const u16x8*)&Blg[bbase];
    *(u16x8*)&Bl[sr][sk + 8] = *(const u16x8*)&Blg[bbase + 8];
    __syncthreads();
    short8 ah[4], al[4], bh[4], bl[4];
    #pragma unroll
    for (int mi = 0; mi < 4; ++mi) {
      ah[mi] = *(const short8*)&Ah[wr + mi * 16 + fr][fk];
      al[mi] = *(const short8*)&Al[wr + mi * 16 + fr][fk];
    }
    #pragma unroll
    for (int ni = 0; ni < 4; ++ni) {
      bh[ni] = *(const short8*)&Bh[wc + ni * 16 + fr][fk];
      bl[ni] = *(const short8*)&Bl[wc + ni * 16 + fr][fk];
    }
    #pragma unroll
    for (int mi = 0; mi < 4; ++mi)
      #pragma unroll
      for (int ni = 0; ni < 4; ++ni) {
        acc[mi][ni] = __builtin_amdgcn_mfma_f32_16x16x32_bf16(ah[mi], bh[ni], acc[mi][ni], 0, 0, 0);
        acc[mi][ni] = __builtin_amdgcn_mfma_f32_16x16x32_bf16(ah[mi], bl[ni], acc[mi][ni], 0, 0, 0);
        acc[mi][ni] = __builtin_amdgcn_mfma_f32_16x16x32_bf16(al[mi], bh[ni], acc[mi][ni], 0, 0, 0);
      }
    __syncthreads();
  }
  const int fq = (lane >> 4) * 4;
  // C write
  #pragma unroll
  for (int mi = 0; mi < 4; ++mi)
    #pragma unroll
    for (int ni = 0; ni < 4; ++ni)
      #pragma unroll
      for (int q = 0; q < 4; ++q) {
        int row = n0 + wr + mi * 16 + fq + q;
        int col = m0 + wc + ni * 16 + fr;
        float x = acc[mi][ni][q];
        if (EPI == 0) {
          unsigned short h = f2bf(x);
          outh[(size_t)row * 256 + col] = h;
          outl[(size_t)row * 256 + col] = f2bf(x - bf2f(h));
        } else {
          outf[coff + (size_t)row * ldC + col] = x;
        }
      }
  if (EPI == 1) {
    // Stat buffers alias the dead frag LDS (all waves past last frag read).
    float2 (*rowbuf)[2] = (float2(*)[2])&Ah[0][0];
    float2 (*colbuf)[2] = (float2(*)[2])&Bh[0][0];
    // ROW partials: per (mi,q) row, reduce over ni (in-thread) then fr lanes.
    #pragma unroll
    for (int mi = 0; mi < 4; ++mi)
      #pragma unroll
      for (int q = 0; q < 4; ++q) {
        float v0 = acc[mi][0][q], v1 = acc[mi][1][q], v2 = acc[mi][2][q], v3 = acc[mi][3][q];
        float mx = fmaxf(fmaxf(v0, v1), fmaxf(v2, v3));
        #pragma unroll
        for (int mask = 1; mask <= 8; mask <<= 1) mx = fmaxf(mx, __shfl_xor(mx, mask));
        float se = __expf(v0 - mx) + __expf(v1 - mx) + __expf(v2 - mx) + __expf(v3 - mx);
        #pragma unroll
        for (int mask = 1; mask <= 8; mask <<= 1) se += __shfl_xor(se, mask);
        if (fr == 0) rowbuf[wr + mi * 16 + fq + q][w & 1] = make_float2(mx, se);
      }
    // COL partials: per ni col, reduce in-thread then lane-groups 16/32.
    #pragma unroll
    for (int ni = 0; ni < 4; ++ni) {
      float mx = -INFINITY;
      #pragma unroll
      for (int mi = 0; mi < 4; ++mi)
        #pragma unroll
        for (int q = 0; q < 4; ++q) mx = fmaxf(mx, acc[mi][ni][q]);
      mx = fmaxf(mx, __shfl_xor(mx, 16));
      mx = fmaxf(mx, __shfl_xor(mx, 32));
      float se = 0.f;
      #pragma unroll
      for (int mi = 0; mi < 4; ++mi)
        #pragma unroll
        for (int q = 0; q < 4; ++q) se += __expf(acc[mi][ni][q] - mx);
      se += __shfl_xor(se, 16);
      se += __shfl_xor(se, 32);
      if ((lane >> 4) == 0) colbuf[wc + ni * 16 + fr][w >> 1] = make_float2(mx, se);
    }
    __syncthreads();
    if (tid < 128) {
      float2 a = rowbuf[tid][0], c = rowbuf[tid][1];
      float nm = fmaxf(a.x, c.x);
      float s = a.y * __expf(a.x - nm) + c.y * __expf(c.x - nm);
      prow[((size_t)g * NN + n0 + tid) * 8 + blockIdx.y] = make_float2(nm, s);
    } else {
      int m = tid - 128;
      float2 a = colbuf[m][0], c = colbuf[m][1];
      float nm = fmaxf(a.x, c.x);
      float s = a.y * __expf(a.x - nm) + c.y * __expf(c.x - nm);
      pcol[((size_t)g * NN + m0 + m) * 8 + blockIdx.x] = make_float2(nm, s);
    }
  }
}

// ---------------------------------------------------------------------------
// k_comb: merge 8 (max,sumexp) partials -> lse = max + log(sum).
// ---------------------------------------------------------------------------
__global__ __launch_bounds__(256) void k_comb(const float2* __restrict__ part,
                                              float* __restrict__ lse, int b0) {
  const int g = blockIdx.y, b = b0 + g;
  const int i = blockIdx.x * 256 + threadIdx.x;
  float mx = -INFINITY, sum = 0.f;
  #pragma unroll
  for (int c = 0; c < 8; ++c) {
    float2 p = part[((size_t)g * NN + i) * 8 + c];
    float nm = fmaxf(mx, p.x);
    sum = sum * __expf(mx - nm) + p.y * __expf(p.x - nm);
    mx = nm;
  }
  lse[(size_t)b * NN + i] = mx + __logf(sum);
}

// ---------------------------------------------------------------------------
// k_pexp: s[n][m] f32 -> two transposed bf16 P operands:
//   P1T[m][n] = exp(s[n][m] - lc[m])   (t_weight, softmax over n)
//   P2T[m][n] = exp(s[n][m] - lr[n])   (f_weight, softmax over m)
// 64x64 tile via padded-LDS transpose; coalesced reads and writes.
// ---------------------------------------------------------------------------
__global__ __launch_bounds__(256) void k_pexp(const float* __restrict__ s,
                                              const float* __restrict__ lr,
                                              const float* __restrict__ lc,
                                              unsigned short* __restrict__ P1T,
                                              unsigned short* __restrict__ P2T,
                                              int b0) {
  const int g = blockIdx.z, b = b0 + g;
  const int n0 = blockIdx.x * 64, m0 = blockIdx.y * 64;
  const float* S = s + (size_t)g * NN * NN;
  __shared__ float Ls[64][65];
  __shared__ float lrs[64], lcs[64];
  const int tid = threadIdx.x;
  const int r = tid >> 4, c4 = (tid & 15) * 4;
  #pragma unroll
  for (int rr = 0; rr < 4; ++rr) {
    int row = r + rr * 16;
    float4 v = *(const float4*)&S[(size_t)(n0 + row) * NN + m0 + c4];
    *(float4*)&Ls[row][c4] = v;
  }
  if (tid < 64) {
    lrs[tid] = lr[(size_t)b * NN + n0 + tid];
    lcs[tid] = lc[(size_t)b * NN + m0 + tid];
  }
  __syncthreads();
  const int oct = tid & 7, ml = tid >> 3;  // ml 0..31
  #pragma unroll
  for (int mm2 = 0; mm2 < 2; ++mm2) {
    int mm = ml + mm2 * 32;
    float lcv = lcs[mm];
    u16x8 p1, p2;
    #pragma unroll
    for (int j = 0; j < 8; ++j) {
      int nl = oct * 8 + j;
      float v = Ls[nl][mm];
      p1[j] = f2bf_fast(__expf(v - lcv));
      p2[j] = f2bf_fast(__expf(v - lrs[nl]));
    }
    size_t dst = ((size_t)g * NN + m0 + mm) * NN + n0 + oct * 8;
    *(u16x8*)&P1T[dst] = p1;
    *(u16x8*)&P2T[dst] = p2;
  }
}

// ---------------------------------------------------------------------------
// k_outg2: out[d][m] = sum_n AT[d][n] * PT[m][n]  — pure bf16 NT GEMM.
// 128x128 tile, 4 waves, 1 MFMA per frag pair.
// ---------------------------------------------------------------------------
__global__ __launch_bounds__(256) void k_outg2(const unsigned short* __restrict__ ATg,
                                               const unsigned short* __restrict__ PT,
                                               float* __restrict__ out, int b0) {
  const int g = blockIdx.z, b = b0 + g;
  const int m0 = blockIdx.x * 128, d0 = blockIdx.y * 128;
  const unsigned short* A = ATg + (size_t)b * DD * NN;  // [d][n]
  const unsigned short* Bm = PT + (size_t)g * NN * NN;  // [m][n]
  float* O = out + (size_t)b * DD * NN;                 // [d][m]
  __shared__ unsigned short Ah[128][LDK], Bh[128][LDK];
  const int tid = threadIdx.x;
  const int lane = tid & 63, w = tid >> 6;
  const int wr = (w >> 1) * 64, wc = (w & 1) * 64;
  const int sr = tid >> 1, sk = (tid & 1) * 16;
  f32x4 acc[4][4] = {};
  const int fr = lane & 15, fk = (lane >> 4) * 8;
  for (int k0 = 0; k0 < NN; k0 += KSTEP) {
    const size_t abase = (size_t)(d0 + sr) * NN + k0 + sk;
    const size_t bbase = (size_t)(m0 + sr) * NN + k0 + sk;
    *(u16x8*)&Ah[sr][sk] = *(const u16x8*)&A[abase];
    *(u16x8*)&Ah[sr][sk + 8] = *(const u16x8*)&A[abase + 8];
    *(u16x8*)&Bh[sr][sk] = *(const u16x8*)&Bm[bbase];
    *(u16x8*)&Bh[sr][sk + 8] = *(const u16x8*)&Bm[bbase + 8];
    __syncthreads();
    short8 af[4], bf[4];
    #pragma unroll
    for (int mi = 0; mi < 4; ++mi) af[mi] = *(const short8*)&Ah[wr + mi * 16 + fr][fk];
    #pragma unroll
    for (int ni = 0; ni < 4; ++ni) bf[ni] = *(const short8*)&Bh[wc + ni * 16 + fr][fk];
    #pragma unroll
    for (int mi = 0; mi < 4; ++mi)
      #pragma unroll
      for (int ni = 0; ni < 4; ++ni)
        acc[mi][ni] = __builtin_amdgcn_mfma_f32_16x16x32_bf16(af[mi], bf[ni], acc[mi][ni], 0, 0, 0);
    __syncthreads();
  }
  const int fq = (lane >> 4) * 4;
  #pragma unroll
  for (int mi = 0; mi < 4; ++mi)
    #pragma unroll
    for (int ni = 0; ni < 4; ++ni)
      #pragma unroll
      for (int q = 0; q < 4; ++q)
        O[(size_t)(d0 + wr + mi * 16 + fq + q) * NN + m0 + wc + ni * 16 + fr] = acc[mi][ni][q];
}

// ---------------------------------------------------------------------------
extern "C" void kernel_launch(void* const* d_in, const int* in_sizes, int n_in,
                              void* d_out, int out_size, void* d_ws, size_t ws_size,
                              hipStream_t stream) {
  const float* t = (const float*)d_in[0];
  const float* f = (const float*)d_in[1];
  const float* W = (const float*)d_in[2];
  float* out = (float*)d_out;

  const size_t NE = (size_t)BB * NN * DD;
  char* ws = (char*)d_ws;
  size_t off = 0;
  auto alloc = [&](size_t bytes) { char* p = ws + off; off += (bytes + 255) & ~(size_t)255; return p; };
  unsigned short* t_hi = (unsigned short*)alloc(NE * 2);
  unsigned short* t_lo = (unsigned short*)alloc(NE * 2);
  unsigned short* f_hi = (unsigned short*)alloc(NE * 2);
  unsigned short* f_lo = (unsigned short*)alloc(NE * 2);
  unsigned short* tw_hi = (unsigned short*)alloc(NE * 2);
  unsigned short* tw_lo = (unsigned short*)alloc(NE * 2);
  unsigned short* tT = (unsigned short*)alloc(NE * 2);
  unsigned short* fT = (unsigned short*)alloc(NE * 2);
  unsigned short* Wth = (unsigned short*)alloc((size_t)DD * DD * 2);
  unsigned short* Wtl = (unsigned short*)alloc((size_t)DD * DD * 2);
  float* lr = (float*)alloc((size_t)BB * NN * 4);
  float* lc = (float*)alloc((size_t)BB * NN * 4);
  float2* prow = (float2*)alloc((size_t)BB * NN * 8 * 8);
  float2* pcol = (float2*)alloc((size_t)BB * NN * 8 * 8);
  size_t fixed_bytes = off;
  // per-batch group region: sbuf (f32 NN*NN) + P1T + P2T (bf16 NN*NN each) = 8 MB
  size_t per_batch = (size_t)NN * NN * 4 + (size_t)NN * NN * 2 * 2;
  int G = 1;
  if (ws_size > fixed_bytes + per_batch) {
    size_t avail = (ws_size - fixed_bytes) / per_batch;
    G = (int)(avail < BB ? avail : BB);
    if (G < 1) G = 1;
  }
  float* sbuf = (float*)(ws + fixed_bytes);
  unsigned short* P1T = (unsigned short*)(ws + fixed_bytes + (size_t)G * NN * NN * 4);
  unsigned short* P2T = P1T + (size_t)G * NN * NN;

  float* out_t = out;
  float* out_f = out + (size_t)BB * DD * NN;

  // Prologue
  k_split<<<(int)((NE / 4 + 255) / 256), 256, 0, stream>>>(t, t_hi, t_lo, (int)(NE / 4));
  k_split<<<(int)((NE / 4 + 255) / 256), 256, 0, stream>>>(f, f_hi, f_lo, (int)(NE / 4));
  k_splitW<<<DD, DD, 0, stream>>>(W, Wth, Wtl);
  k_transT<<<dim3(NN / 64, DD / 64, BB), 256, 0, stream>>>(t_hi, tT);
  k_transT<<<dim3(NN / 64, DD / 64, BB), 256, 0, stream>>>(f_hi, fT);
  k_gemm_nt<0><<<dim3(256, 2, 1), 256, 0, stream>>>(t_hi, t_lo, Wth, Wtl, tw_hi, tw_lo,
                                                    nullptr, nullptr, nullptr, 0);

  for (int b0 = 0; b0 < BB; b0 += G) {
    int g = BB - b0 < G ? BB - b0 : G;
    k_gemm_nt<1><<<dim3(8, 8, g), 256, 0, stream>>>(tw_hi, tw_lo, f_hi, f_lo, nullptr, nullptr,
                                                    sbuf, prow, pcol, b0);
    k_comb<<<dim3(NN / 256, g), 256, 0, stream>>>(prow, lr, b0);
    k_comb<<<dim3(NN / 256, g), 256, 0, stream>>>(pcol, lc, b0);
    k_pexp<<<dim3(NN / 64, NN / 64, g), 256, 0, stream>>>(sbuf, lr, lc, P1T, P2T, b0);
    k_outg2<<<dim3(8, 2, g), 256, 0, stream>>>(tT, P1T, out_t, b0);
    k_outg2<<<dim3(8, 2, g), 256, 0, stream>>>(fT, P2T, out_f, b0);
  }
}

// Round 8
// 368.258 us; speedup vs baseline: 1.4638x; 1.4412x over previous
//
#include <hip/hip_runtime.h>
#include <math.h>

#define BB 32
#define NN 1024
#define DD 256
#define KSTEP 32
#define LDK 40   // bf16 LDS row stride (shorts): 80B rows, spread banks, 16B aligned

typedef __attribute__((ext_vector_type(8))) short short8;
typedef __attribute__((ext_vector_type(8))) unsigned short u16x8;
typedef __attribute__((ext_vector_type(4))) float f32x4;

__device__ __forceinline__ unsigned short f2bf(float x) {  // round-nearest-even (split path)
  unsigned u = __float_as_uint(x);
  return (unsigned short)((u + 0x7fffu + ((u >> 16) & 1u)) >> 16);
}
__device__ __forceinline__ unsigned short f2bf_fast(float x) {  // round-half-up (P values)
  return (unsigned short)((__float_as_uint(x) + 0x8000u) >> 16);
}
__device__ __forceinline__ float bf2f(unsigned short h) {
  return __uint_as_float((unsigned)h << 16);
}

// ---------------------------------------------------------------------------
// k_split: f32 -> bf16 hi/lo, float4-vectorized.
// ---------------------------------------------------------------------------
__global__ __launch_bounds__(256) void k_split(const float* __restrict__ src,
                                               unsigned short* __restrict__ hi,
                                               unsigned short* __restrict__ lo, int n4) {
  int i = blockIdx.x * 256 + threadIdx.x;
  if (i >= n4) return;
  float4 v = ((const float4*)src)[i];
  float xs[4] = {v.x, v.y, v.z, v.w};
  ushort4 h4, l4;
  unsigned short* hp = (unsigned short*)&h4;
  unsigned short* lp = (unsigned short*)&l4;
  #pragma unroll
  for (int j = 0; j < 4; ++j) {
    unsigned short h = f2bf(xs[j]);
    hp[j] = h;
    lp[j] = f2bf(xs[j] - bf2f(h));
  }
  ((ushort4*)hi)[i] = h4;
  ((ushort4*)lo)[i] = l4;
}

// W [k][n] -> Wt [n][k], split hi/lo.
__global__ __launch_bounds__(256) void k_splitW(const float* __restrict__ W,
                                                unsigned short* __restrict__ Wth,
                                                unsigned short* __restrict__ Wtl) {
  int k = blockIdx.x, n = threadIdx.x;
  float x = W[k * DD + n];
  unsigned short h = f2bf(x);
  Wth[n * DD + k] = h;
  Wtl[n * DD + k] = f2bf(x - bf2f(h));
}

// ---------------------------------------------------------------------------
// k_transT: bf16 [BB*NN][DD] -> [BB][DD][NN]. Strided reads L1-amortized,
// writes coalesced.
// ---------------------------------------------------------------------------
__global__ __launch_bounds__(256) void k_transT(const unsigned short* __restrict__ in,
                                                unsigned short* __restrict__ out) {
  const int b = blockIdx.z;
  const int n0 = blockIdx.x * 64, d0 = blockIdx.y * 64;
  const int tid = threadIdx.x;
  const int nl = tid & 63, dc = tid >> 6;
  #pragma unroll
  for (int dj = 0; dj < 16; ++dj) {
    int d = d0 + dc * 16 + dj;
    unsigned short v = in[((size_t)b * NN + n0 + nl) * DD + d];
    out[((size_t)b * DD + d) * NN + n0 + nl] = v;
  }
}

// ---------------------------------------------------------------------------
// k_gemm_nt<EPI>: C = A @ B^T, split-bf16 (3 MFMAs). 128x128 tile, 4 waves.
//   EPI 0 (tW): C -> bf16 hi/lo (row-major).
//   EPI 1 (s):  C -> f32 TRANSPOSED sT[m][n] (float4 stores), plus fused
//               row/col (max,sumexp) partials (stat bufs alias frag LDS).
// ---------------------------------------------------------------------------
template <int EPI>
__global__ __launch_bounds__(256) void k_gemm_nt(const unsigned short* __restrict__ Ahg,
                                                 const unsigned short* __restrict__ Alg,
                                                 const unsigned short* __restrict__ Bhg,
                                                 const unsigned short* __restrict__ Blg,
                                                 unsigned short* __restrict__ outh,
                                                 unsigned short* __restrict__ outl,
                                                 float* __restrict__ outf,
                                                 float2* __restrict__ prow,
                                                 float2* __restrict__ pcol, int b0) {
  size_t aoff = 0, boff = 0, coff = 0;
  const int g = blockIdx.z;
  if (EPI == 1) {
    int b = b0 + g;
    aoff = (size_t)b * NN * DD;
    boff = (size_t)b * NN * DD;
    coff = (size_t)g * NN * NN;
  }
  const int n0 = blockIdx.x * 128, m0 = blockIdx.y * 128;
  __shared__ unsigned short Ah[128][LDK], Al[128][LDK], Bh[128][LDK], Bl[128][LDK];
  const int tid = threadIdx.x;
  const int lane = tid & 63, w = tid >> 6;
  const int wr = (w >> 1) * 64, wc = (w & 1) * 64;
  const int sr = tid >> 1, sk = (tid & 1) * 16;

  f32x4 acc[4][4] = {};
  const int fr = lane & 15, fk = (lane >> 4) * 8;

  for (int k0 = 0; k0 < DD; k0 += KSTEP) {
    const size_t abase = aoff + (size_t)(n0 + sr) * DD + k0 + sk;
    const size_t bbase = boff + (size_t)(m0 + sr) * DD + k0 + sk;
    *(u16x8*)&Ah[sr][sk] = *(const u16x8*)&Ahg[abase];
    *(u16x8*)&Ah[sr][sk + 8] = *(const u16x8*)&Ahg[abase + 8];
    *(u16x8*)&Al[sr][sk] = *(const u16x8*)&Alg[abase];
    *(u16x8*)&Al[sr][sk + 8] = *(const u16x8*)&Alg[abase + 8];
    *(u16x8*)&Bh[sr][sk] = *(const u16x8*)&Bhg[bbase];
    *(u16x8*)&Bh[sr][sk + 8] = *(const u16x8*)&Bhg[bbase + 8];
    *(u16x8*)&Bl[sr][sk] = *(const u16x8*)&Blg[bbase];
    *(u16x8*)&Bl[sr][sk + 8] = *(const u16x8*)&Blg[bbase + 8];
    __syncthreads();
    short8 ah[4], al[4], bh[4], bl[4];
    #pragma unroll
    for (int mi = 0; mi < 4; ++mi) {
      ah[mi] = *(const short8*)&Ah[wr + mi * 16 + fr][fk];
      al[mi] = *(const short8*)&Al[wr + mi * 16 + fr][fk];
    }
    #pragma unroll
    for (int ni = 0; ni < 4; ++ni) {
      bh[ni] = *(const short8*)&Bh[wc + ni * 16 + fr][fk];
      bl[ni] = *(const short8*)&Bl[wc + ni * 16 + fr][fk];
    }
    #pragma unroll
    for (int mi = 0; mi < 4; ++mi)
      #pragma unroll
      for (int ni = 0; ni < 4; ++ni) {
        acc[mi][ni] = __builtin_amdgcn_mfma_f32_16x16x32_bf16(ah[mi], bh[ni], acc[mi][ni], 0, 0, 0);
        acc[mi][ni] = __builtin_amdgcn_mfma_f32_16x16x32_bf16(ah[mi], bl[ni], acc[mi][ni], 0, 0, 0);
        acc[mi][ni] = __builtin_amdgcn_mfma_f32_16x16x32_bf16(al[mi], bh[ni], acc[mi][ni], 0, 0, 0);
      }
    __syncthreads();
  }
  const int fq = (lane >> 4) * 4;
  if (EPI == 0) {
    #pragma unroll
    for (int mi = 0; mi < 4; ++mi)
      #pragma unroll
      for (int ni = 0; ni < 4; ++ni)
        #pragma unroll
        for (int q = 0; q < 4; ++q) {
          int row = n0 + wr + mi * 16 + fq + q;
          int col = m0 + wc + ni * 16 + fr;
          float x = acc[mi][ni][q];
          unsigned short h = f2bf(x);
          outh[(size_t)row * 256 + col] = h;
          outl[(size_t)row * 256 + col] = f2bf(x - bf2f(h));
        }
  } else {
    // Transposed store: sT[m][n], per lane one float4 of 4 consecutive n.
    #pragma unroll
    for (int mi = 0; mi < 4; ++mi)
      #pragma unroll
      for (int ni = 0; ni < 4; ++ni) {
        int colm = m0 + wc + ni * 16 + fr;
        int nbase = n0 + wr + mi * 16 + fq;
        float4 v = {acc[mi][ni][0], acc[mi][ni][1], acc[mi][ni][2], acc[mi][ni][3]};
        *(float4*)&outf[coff + (size_t)colm * NN + nbase] = v;
      }
    // Stat buffers alias the dead frag LDS.
    float2 (*rowbuf)[2] = (float2(*)[2])&Ah[0][0];
    float2 (*colbuf)[2] = (float2(*)[2])&Bh[0][0];
    #pragma unroll
    for (int mi = 0; mi < 4; ++mi)
      #pragma unroll
      for (int q = 0; q < 4; ++q) {
        float v0 = acc[mi][0][q], v1 = acc[mi][1][q], v2 = acc[mi][2][q], v3 = acc[mi][3][q];
        float mx = fmaxf(fmaxf(v0, v1), fmaxf(v2, v3));
        #pragma unroll
        for (int mask = 1; mask <= 8; mask <<= 1) mx = fmaxf(mx, __shfl_xor(mx, mask));
        float se = __expf(v0 - mx) + __expf(v1 - mx) + __expf(v2 - mx) + __expf(v3 - mx);
        #pragma unroll
        for (int mask = 1; mask <= 8; mask <<= 1) se += __shfl_xor(se, mask);
        if (fr == 0) rowbuf[wr + mi * 16 + fq + q][w & 1] = make_float2(mx, se);
      }
    #pragma unroll
    for (int ni = 0; ni < 4; ++ni) {
      float mx = -INFINITY;
      #pragma unroll
      for (int mi = 0; mi < 4; ++mi)
        #pragma unroll
        for (int q = 0; q < 4; ++q) mx = fmaxf(mx, acc[mi][ni][q]);
      mx = fmaxf(mx, __shfl_xor(mx, 16));
      mx = fmaxf(mx, __shfl_xor(mx, 32));
      float se = 0.f;
      #pragma unroll
      for (int mi = 0; mi < 4; ++mi)
        #pragma unroll
        for (int q = 0; q < 4; ++q) se += __expf(acc[mi][ni][q] - mx);
      se += __shfl_xor(se, 16);
      se += __shfl_xor(se, 32);
      if ((lane >> 4) == 0) colbuf[wc + ni * 16 + fr][w >> 1] = make_float2(mx, se);
    }
    __syncthreads();
    if (tid < 128) {
      float2 a = rowbuf[tid][0], c = rowbuf[tid][1];
      float nm = fmaxf(a.x, c.x);
      float s = a.y * __expf(a.x - nm) + c.y * __expf(c.x - nm);
      prow[((size_t)g * NN + n0 + tid) * 8 + blockIdx.y] = make_float2(nm, s);
    } else {
      int m = tid - 128;
      float2 a = colbuf[m][0], c = colbuf[m][1];
      float nm = fmaxf(a.x, c.x);
      float s = a.y * __expf(a.x - nm) + c.y * __expf(c.x - nm);
      pcol[((size_t)g * NN + m0 + m) * 8 + blockIdx.x] = make_float2(nm, s);
    }
  }
}

// ---------------------------------------------------------------------------
// k_comb: merge 8 (max,sumexp) partials -> lse = max + log(sum).
// ---------------------------------------------------------------------------
__global__ __launch_bounds__(256) void k_comb(const float2* __restrict__ part,
                                              float* __restrict__ lse, int b0) {
  const int g = blockIdx.y, b = b0 + g;
  const int i = blockIdx.x * 256 + threadIdx.x;
  float mx = -INFINITY, sum = 0.f;
  #pragma unroll
  for (int c = 0; c < 8; ++c) {
    float2 p = part[((size_t)g * NN + i) * 8 + c];
    float nm = fmaxf(mx, p.x);
    sum = sum * __expf(mx - nm) + p.y * __expf(p.x - nm);
    mx = nm;
  }
  lse[(size_t)b * NN + i] = mx + __logf(sum);
}

// ---------------------------------------------------------------------------
// k_outdual: BOTH outputs in one pass over sT[c][r]:
//   out_t[d][c] = sum_r tT[d][r] * exp(sT[c][r] - lc[c])
//   out_f[d][c] = sum_r fT[d][r] * exp(sT[c][r] - lr[r])
// Tile: c=64, d=128, 4 waves (2d x 2c), wave-tile 64d x 32c. All staging
// vectorized; P operands built in registers (16 exps/thread/k-step).
// ---------------------------------------------------------------------------
__global__ __launch_bounds__(256) void k_outdual(const unsigned short* __restrict__ tTg,
                                                 const unsigned short* __restrict__ fTg,
                                                 const float* __restrict__ sT,
                                                 const float* __restrict__ lr,
                                                 const float* __restrict__ lc,
                                                 float* __restrict__ out_t,
                                                 float* __restrict__ out_f, int b0) {
  const int g = blockIdx.z, b = b0 + g;
  const int c0 = blockIdx.x * 64;
  const int d0 = blockIdx.y * 128;
  const unsigned short* At = tTg + (size_t)b * DD * NN;  // [d][r]
  const unsigned short* Af = fTg + (size_t)b * DD * NN;
  const float* S = sT + (size_t)g * NN * NN;             // [c][r]
  __shared__ unsigned short Ats[128][LDK], Afs[128][LDK];
  __shared__ unsigned short P1s[64][LDK], P2s[64][LDK];
  const int tid = threadIdx.x;
  const int lane = tid & 63, w = tid >> 6;
  const int wd = (w >> 1) * 64, wcc = (w & 1) * 32;
  const int fr = lane & 15, fk = (lane >> 4) * 8, fq = (lane >> 4) * 4;
  const int ar = tid >> 1, ak = (tid & 1) * 16;     // A staging: row, k-off
  const int srow = tid >> 2, soff = (tid & 3) * 8;  // S staging: c-row, 8 r-vals
  const float lcv = lc[(size_t)b * NN + c0 + srow]; // per-thread constant
  f32x4 acc1[4][2] = {}, acc2[4][2] = {};
  for (int r0 = 0; r0 < NN; r0 += KSTEP) {
    const size_t arow = (size_t)(d0 + ar) * NN + r0 + ak;
    u16x8 a_t0 = *(const u16x8*)&At[arow];
    u16x8 a_t1 = *(const u16x8*)&At[arow + 8];
    u16x8 a_f0 = *(const u16x8*)&Af[arow];
    u16x8 a_f1 = *(const u16x8*)&Af[arow + 8];
    float4 v0 = *(const float4*)&S[(size_t)(c0 + srow) * NN + r0 + soff];
    float4 v1 = *(const float4*)&S[(size_t)(c0 + srow) * NN + r0 + soff + 4];
    float4 l0 = *(const float4*)&lr[(size_t)b * NN + r0 + soff];
    float4 l1 = *(const float4*)&lr[(size_t)b * NN + r0 + soff + 4];
    float sv[8] = {v0.x, v0.y, v0.z, v0.w, v1.x, v1.y, v1.z, v1.w};
    float lv[8] = {l0.x, l0.y, l0.z, l0.w, l1.x, l1.y, l1.z, l1.w};
    u16x8 p1, p2;
    #pragma unroll
    for (int j = 0; j < 8; ++j) {
      p1[j] = f2bf_fast(__expf(sv[j] - lcv));
      p2[j] = f2bf_fast(__expf(sv[j] - lv[j]));
    }
    __syncthreads();  // prev-iter frag reads done before overwrite
    *(u16x8*)&Ats[ar][ak] = a_t0;
    *(u16x8*)&Ats[ar][ak + 8] = a_t1;
    *(u16x8*)&Afs[ar][ak] = a_f0;
    *(u16x8*)&Afs[ar][ak + 8] = a_f1;
    *(u16x8*)&P1s[srow][soff] = p1;
    *(u16x8*)&P2s[srow][soff] = p2;
    __syncthreads();
    short8 at[4], af[4], b1[2], b2[2];
    #pragma unroll
    for (int mi = 0; mi < 4; ++mi) {
      at[mi] = *(const short8*)&Ats[wd + mi * 16 + fr][fk];
      af[mi] = *(const short8*)&Afs[wd + mi * 16 + fr][fk];
    }
    #pragma unroll
    for (int ci = 0; ci < 2; ++ci) {
      b1[ci] = *(const short8*)&P1s[wcc + ci * 16 + fr][fk];
      b2[ci] = *(const short8*)&P2s[wcc + ci * 16 + fr][fk];
    }
    #pragma unroll
    for (int mi = 0; mi < 4; ++mi)
      #pragma unroll
      for (int ci = 0; ci < 2; ++ci) {
        acc1[mi][ci] = __builtin_amdgcn_mfma_f32_16x16x32_bf16(at[mi], b1[ci], acc1[mi][ci], 0, 0, 0);
        acc2[mi][ci] = __builtin_amdgcn_mfma_f32_16x16x32_bf16(af[mi], b2[ci], acc2[mi][ci], 0, 0, 0);
      }
  }
  float* Ot = out_t + (size_t)b * DD * NN;
  float* Of = out_f + (size_t)b * DD * NN;
  #pragma unroll
  for (int mi = 0; mi < 4; ++mi)
    #pragma unroll
    for (int ci = 0; ci < 2; ++ci)
      #pragma unroll
      for (int q = 0; q < 4; ++q) {
        int d = d0 + wd + mi * 16 + fq + q;
        int c = c0 + wcc + ci * 16 + fr;
        Ot[(size_t)d * NN + c] = acc1[mi][ci][q];
        Of[(size_t)d * NN + c] = acc2[mi][ci][q];
      }
}

// ---------------------------------------------------------------------------
extern "C" void kernel_launch(void* const* d_in, const int* in_sizes, int n_in,
                              void* d_out, int out_size, void* d_ws, size_t ws_size,
                              hipStream_t stream) {
  const float* t = (const float*)d_in[0];
  const float* f = (const float*)d_in[1];
  const float* W = (const float*)d_in[2];
  float* out = (float*)d_out;

  const size_t NE = (size_t)BB * NN * DD;
  char* ws = (char*)d_ws;
  size_t off = 0;
  auto alloc = [&](size_t bytes) { char* p = ws + off; off += (bytes + 255) & ~(size_t)255; return p; };
  // Buffers live past the prologue:
  unsigned short* f_hi = (unsigned short*)alloc(NE * 2);
  unsigned short* f_lo = (unsigned short*)alloc(NE * 2);
  unsigned short* tw_hi = (unsigned short*)alloc(NE * 2);
  unsigned short* tw_lo = (unsigned short*)alloc(NE * 2);
  unsigned short* tT = (unsigned short*)alloc(NE * 2);
  unsigned short* fT = (unsigned short*)alloc(NE * 2);
  unsigned short* Wth = (unsigned short*)alloc((size_t)DD * DD * 2);
  unsigned short* Wtl = (unsigned short*)alloc((size_t)DD * DD * 2);
  float* lr = (float*)alloc((size_t)BB * NN * 4);
  float* lc = (float*)alloc((size_t)BB * NN * 4);
  float2* prow = (float2*)alloc((size_t)BB * NN * 8 * 8);
  float2* pcol = (float2*)alloc((size_t)BB * NN * 8 * 8);
  size_t fixed_bytes = off;
  // sbuf region; t_hi/t_lo ALIAS its start (dead after prologue, stream-ordered).
  float* sbuf = (float*)(ws + fixed_bytes);
  unsigned short* t_hi = (unsigned short*)(ws + fixed_bytes);
  unsigned short* t_lo = t_hi + NE;
  size_t per_batch = (size_t)NN * NN * 4;
  int G = 1;
  if (ws_size > fixed_bytes + per_batch) {
    size_t avail = (ws_size - fixed_bytes) / per_batch;
    G = (int)(avail < BB ? avail : BB);
    if (G < 1) G = 1;
  }

  float* out_t = out;
  float* out_f = out + (size_t)BB * DD * NN;

  // Prologue
  k_split<<<(int)((NE / 4 + 255) / 256), 256, 0, stream>>>(t, t_hi, t_lo, (int)(NE / 4));
  k_split<<<(int)((NE / 4 + 255) / 256), 256, 0, stream>>>(f, f_hi, f_lo, (int)(NE / 4));
  k_splitW<<<DD, DD, 0, stream>>>(W, Wth, Wtl);
  k_transT<<<dim3(NN / 64, DD / 64, BB), 256, 0, stream>>>(t_hi, tT);
  k_transT<<<dim3(NN / 64, DD / 64, BB), 256, 0, stream>>>(f_hi, fT);
  k_gemm_nt<0><<<dim3(256, 2, 1), 256, 0, stream>>>(t_hi, t_lo, Wth, Wtl, tw_hi, tw_lo,
                                                    nullptr, nullptr, nullptr, 0);

  for (int b0 = 0; b0 < BB; b0 += G) {
    int g = BB - b0 < G ? BB - b0 : G;
    k_gemm_nt<1><<<dim3(8, 8, g), 256, 0, stream>>>(tw_hi, tw_lo, f_hi, f_lo, nullptr, nullptr,
                                                    sbuf, prow, pcol, b0);
    k_comb<<<dim3(NN / 256, g), 256, 0, stream>>>(prow, lr, b0);
    k_comb<<<dim3(NN / 256, g), 256, 0, stream>>>(pcol, lc, b0);
    k_outdual<<<dim3(NN / 64, DD / 128, g), 256, 0, stream>>>(tT, fT, sbuf, lr, lc,
                                                              out_t, out_f, b0);
  }
}

// Round 10
// 362.174 us; speedup vs baseline: 1.4884x; 1.0168x over previous
//
#include <hip/hip_runtime.h>
#include <math.h>

#define BB 32
#define NN 1024
#define DD 256
#define KSTEP 32
#define LDK 40   // bf16 LDS row stride (shorts): 80B rows, spread banks, 16B aligned

typedef __attribute__((ext_vector_type(8))) short short8;
typedef __attribute__((ext_vector_type(8))) unsigned short u16x8;
typedef __attribute__((ext_vector_type(4))) float f32x4;

__device__ __forceinline__ unsigned short f2bf(float x) {  // round-nearest-even (split path)
  unsigned u = __float_as_uint(x);
  return (unsigned short)((u + 0x7fffu + ((u >> 16) & 1u)) >> 16);
}
__device__ __forceinline__ unsigned short f2bf_fast(float x) {  // round-half-up (P values)
  return (unsigned short)((__float_as_uint(x) + 0x8000u) >> 16);
}
__device__ __forceinline__ float bf2f(unsigned short h) {
  return __uint_as_float((unsigned)h << 16);
}

// ---------------------------------------------------------------------------
// k_split: f32 -> bf16 hi/lo, float4-vectorized.
// ---------------------------------------------------------------------------
__global__ __launch_bounds__(256) void k_split(const float* __restrict__ src,
                                               unsigned short* __restrict__ hi,
                                               unsigned short* __restrict__ lo, int n4) {
  int i = blockIdx.x * 256 + threadIdx.x;
  if (i >= n4) return;
  float4 v = ((const float4*)src)[i];
  float xs[4] = {v.x, v.y, v.z, v.w};
  ushort4 h4, l4;
  unsigned short* hp = (unsigned short*)&h4;
  unsigned short* lp = (unsigned short*)&l4;
  #pragma unroll
  for (int j = 0; j < 4; ++j) {
    unsigned short h = f2bf(xs[j]);
    hp[j] = h;
    lp[j] = f2bf(xs[j] - bf2f(h));
  }
  ((ushort4*)hi)[i] = h4;
  ((ushort4*)lo)[i] = l4;
}

// W [k][n] -> Wt [n][k], split hi/lo.
__global__ __launch_bounds__(256) void k_splitW(const float* __restrict__ W,
                                                unsigned short* __restrict__ Wth,
                                                unsigned short* __restrict__ Wtl) {
  int k = blockIdx.x, n = threadIdx.x;
  float x = W[k * DD + n];
  unsigned short h = f2bf(x);
  Wth[n * DD + k] = h;
  Wtl[n * DD + k] = f2bf(x - bf2f(h));
}

// ---------------------------------------------------------------------------
// k_transT: bf16 [BB*NN][DD] -> [BB][DD][NN].
// ---------------------------------------------------------------------------
__global__ __launch_bounds__(256) void k_transT(const unsigned short* __restrict__ in,
                                                unsigned short* __restrict__ out) {
  const int b = blockIdx.z;
  const int n0 = blockIdx.x * 64, d0 = blockIdx.y * 64;
  const int tid = threadIdx.x;
  const int nl = tid & 63, dc = tid >> 6;
  #pragma unroll
  for (int dj = 0; dj < 16; ++dj) {
    int d = d0 + dc * 16 + dj;
    unsigned short v = in[((size_t)b * NN + n0 + nl) * DD + d];
    out[((size_t)b * DD + d) * NN + n0 + nl] = v;
  }
}

// ---------------------------------------------------------------------------
// k_gemm_nt<EPI>: C = A @ B^T, split-bf16 (3 MFMAs). 128x128 tile, 4 waves.
//   EPI 0 (tW): C -> bf16 hi/lo (row-major).
//   EPI 1 (s):  C -> f32 TRANSPOSED sT[m][n] (float4 stores). Lean epilogue.
// ---------------------------------------------------------------------------
template <int EPI>
__global__ __launch_bounds__(256) void k_gemm_nt(const unsigned short* __restrict__ Ahg,
                                                 const unsigned short* __restrict__ Alg,
                                                 const unsigned short* __restrict__ Bhg,
                                                 const unsigned short* __restrict__ Blg,
                                                 unsigned short* __restrict__ outh,
                                                 unsigned short* __restrict__ outl,
                                                 float* __restrict__ outf, int b0) {
  size_t aoff = 0, boff = 0, coff = 0;
  const int g = blockIdx.z;
  if (EPI == 1) {
    int b = b0 + g;
    aoff = (size_t)b * NN * DD;
    boff = (size_t)b * NN * DD;
    coff = (size_t)g * NN * NN;
  }
  const int n0 = blockIdx.x * 128, m0 = blockIdx.y * 128;
  __shared__ unsigned short Ah[128][LDK], Al[128][LDK], Bh[128][LDK], Bl[128][LDK];
  const int tid = threadIdx.x;
  const int lane = tid & 63, w = tid >> 6;
  const int wr = (w >> 1) * 64, wc = (w & 1) * 64;
  const int sr = tid >> 1, sk = (tid & 1) * 16;

  f32x4 acc[4][4] = {};
  const int fr = lane & 15, fk = (lane >> 4) * 8;

  for (int k0 = 0; k0 < DD; k0 += KSTEP) {
    const size_t abase = aoff + (size_t)(n0 + sr) * DD + k0 + sk;
    const size_t bbase = boff + (size_t)(m0 + sr) * DD + k0 + sk;
    *(u16x8*)&Ah[sr][sk] = *(const u16x8*)&Ahg[abase];
    *(u16x8*)&Ah[sr][sk + 8] = *(const u16x8*)&Ahg[abase + 8];
    *(u16x8*)&Al[sr][sk] = *(const u16x8*)&Alg[abase];
    *(u16x8*)&Al[sr][sk + 8] = *(const u16x8*)&Alg[abase + 8];
    *(u16x8*)&Bh[sr][sk] = *(const u16x8*)&Bhg[bbase];
    *(u16x8*)&Bh[sr][sk + 8] = *(const u16x8*)&Bhg[bbase + 8];
    *(u16x8*)&Bl[sr][sk] = *(const u16x8*)&Blg[bbase];
    *(u16x8*)&Bl[sr][sk + 8] = *(const u16x8*)&Blg[bbase + 8];
    __syncthreads();
    short8 ah[4], al[4], bh[4], bl[4];
    #pragma unroll
    for (int mi = 0; mi < 4; ++mi) {
      ah[mi] = *(const short8*)&Ah[wr + mi * 16 + fr][fk];
      al[mi] = *(const short8*)&Al[wr + mi * 16 + fr][fk];
    }
    #pragma unroll
    for (int ni = 0; ni < 4; ++ni) {
      bh[ni] = *(const short8*)&Bh[wc + ni * 16 + fr][fk];
      bl[ni] = *(const short8*)&Bl[wc + ni * 16 + fr][fk];
    }
    #pragma unroll
    for (int mi = 0; mi < 4; ++mi)
      #pragma unroll
      for (int ni = 0; ni < 4; ++ni) {
        acc[mi][ni] = __builtin_amdgcn_mfma_f32_16x16x32_bf16(ah[mi], bh[ni], acc[mi][ni], 0, 0, 0);
        acc[mi][ni] = __builtin_amdgcn_mfma_f32_16x16x32_bf16(ah[mi], bl[ni], acc[mi][ni], 0, 0, 0);
        acc[mi][ni] = __builtin_amdgcn_mfma_f32_16x16x32_bf16(al[mi], bh[ni], acc[mi][ni], 0, 0, 0);
      }
    __syncthreads();
  }
  const int fq = (lane >> 4) * 4;
  if (EPI == 0) {
    #pragma unroll
    for (int mi = 0; mi < 4; ++mi)
      #pragma unroll
      for (int ni = 0; ni < 4; ++ni)
        #pragma unroll
        for (int q = 0; q < 4; ++q) {
          int row = n0 + wr + mi * 16 + fq + q;
          int col = m0 + wc + ni * 16 + fr;
          float x = acc[mi][ni][q];
          unsigned short h = f2bf(x);
          outh[(size_t)row * 256 + col] = h;
          outl[(size_t)row * 256 + col] = f2bf(x - bf2f(h));
        }
  } else {
    // Transposed store: sT[m][n], per lane one float4 of 4 consecutive n.
    #pragma unroll
    for (int mi = 0; mi < 4; ++mi)
      #pragma unroll
      for (int ni = 0; ni < 4; ++ni) {
        int colm = m0 + wc + ni * 16 + fr;
        int nbase = n0 + wr + mi * 16 + fq;
        float4 v = {acc[mi][ni][0], acc[mi][ni][1], acc[mi][ni][2], acc[mi][ni][3]};
        *(float4*)&outf[coff + (size_t)colm * NN + nbase] = v;
      }
  }
}

// ---------------------------------------------------------------------------
// k_stats: one pass over sT[c][r] computing BOTH lse partials per 64x64 tile.
//   lc[c] (softmax over r): reduce along r (contiguous in sT rows)
//   lr[r] (softmax over c): reduce along c (via padded-LDS transpose reads)
// grid (c-tiles=16, r-tiles=16, g). Partials [g][NN][16] float2, merged later.
// ---------------------------------------------------------------------------
__global__ __launch_bounds__(256) void k_stats(const float* __restrict__ sT,
                                               float2* __restrict__ prow,
                                               float2* __restrict__ pcol) {
  const int g = blockIdx.z;
  const int c0 = blockIdx.x * 64, r0 = blockIdx.y * 64;
  const float* S = sT + (size_t)g * NN * NN;
  __shared__ float Ls[64][65];
  const int tid = threadIdx.x;
  const int row = tid >> 4, c4 = (tid & 15) * 4;
  #pragma unroll
  for (int rr = 0; rr < 4; ++rr) {
    int c = row + rr * 16;
    *(float4*)&Ls[c][c4] = *(const float4*)&S[(size_t)(c0 + c) * NN + r0 + c4];
  }
  __syncthreads();
  // lc partials: 4 threads per c-row, each scans 16 contiguous r.
  {
    const int c = tid >> 2, seg = (tid & 3) * 16;
    float mx = -INFINITY;
    #pragma unroll
    for (int j = 0; j < 16; ++j) mx = fmaxf(mx, Ls[c][seg + j]);
    float se = 0.f;
    #pragma unroll
    for (int j = 0; j < 16; ++j) se += __expf(Ls[c][seg + j] - mx);
    #pragma unroll
    for (int mask = 1; mask <= 2; mask <<= 1) {
      float m2 = __shfl_xor(mx, mask), s2 = __shfl_xor(se, mask);
      float nm = fmaxf(mx, m2);
      se = se * __expf(mx - nm) + s2 * __expf(m2 - nm);
      mx = nm;
    }
    if ((tid & 3) == 0)
      pcol[((size_t)g * NN + c0 + c) * 16 + blockIdx.y] = make_float2(mx, se);
  }
  // lr partials: 4 threads per r-col, each scans 16 c (LDS transposed reads).
  {
    const int r = tid >> 2, seg = (tid & 3) * 16;
    float mx = -INFINITY;
    #pragma unroll
    for (int j = 0; j < 16; ++j) mx = fmaxf(mx, Ls[seg + j][r]);
    float se = 0.f;
    #pragma unroll
    for (int j = 0; j < 16; ++j) se += __expf(Ls[seg + j][r] - mx);
    #pragma unroll
    for (int mask = 1; mask <= 2; mask <<= 1) {
      float m2 = __shfl_xor(mx, mask), s2 = __shfl_xor(se, mask);
      float nm = fmaxf(mx, m2);
      se = se * __expf(mx - nm) + s2 * __expf(m2 - nm);
      mx = nm;
    }
    if ((tid & 3) == 0)
      prow[((size_t)g * NN + r0 + r) * 16 + blockIdx.x] = make_float2(mx, se);
  }
}

// ---------------------------------------------------------------------------
// k_comb16: merge 16 (max,sumexp) partials -> lse = max + log(sum).
// ---------------------------------------------------------------------------
__global__ __launch_bounds__(256) void k_comb16(const float2* __restrict__ part,
                                                float* __restrict__ lse, int b0) {
  const int g = blockIdx.y, b = b0 + g;
  const int i = blockIdx.x * 256 + threadIdx.x;
  float mx = -INFINITY, sum = 0.f;
  #pragma unroll
  for (int c = 0; c < 16; ++c) {
    float2 p = part[((size_t)g * NN + i) * 16 + c];
    float nm = fmaxf(mx, p.x);
    sum = sum * __expf(mx - nm) + p.y * __expf(p.x - nm);
    mx = nm;
  }
  lse[(size_t)b * NN + i] = mx + __logf(sum);
}

// ---------------------------------------------------------------------------
// k_outdual: BOTH outputs in one pass over sT[c][r], 128x128 tile, 4 waves:
//   out_t[d][c] = sum_r tT[d][r] * exp(sT[c][r] - lc[c])
//   out_f[d][c] = sum_r fT[d][r] * exp(sT[c][r] - lr[r])
// Per wave per k-step: 32 MFMAs (4 mi x 4 ci x 2 outputs).
// ---------------------------------------------------------------------------
__global__ __launch_bounds__(256) void k_outdual(const unsigned short* __restrict__ tTg,
                                                 const unsigned short* __restrict__ fTg,
                                                 const float* __restrict__ sT,
                                                 const float* __restrict__ lr,
                                                 const float* __restrict__ lc,
                                                 float* __restrict__ out_t,
                                                 float* __restrict__ out_f, int b0) {
  const int g = blockIdx.z, b = b0 + g;
  const int c0 = blockIdx.x * 128;
  const int d0 = blockIdx.y * 128;
  const unsigned short* At = tTg + (size_t)b * DD * NN;  // [d][r]
  const unsigned short* Af = fTg + (size_t)b * DD * NN;
  const float* S = sT + (size_t)g * NN * NN;             // [c][r]
  __shared__ unsigned short Ats[128][LDK], Afs[128][LDK];
  __shared__ unsigned short P1s[128][LDK], P2s[128][LDK];
  const int tid = threadIdx.x;
  const int lane = tid & 63, w = tid >> 6;
  const int wd = (w >> 1) * 64, wcc = (w & 1) * 64;
  const int fr = lane & 15, fk = (lane >> 4) * 8, fq = (lane >> 4) * 4;
  const int ar = tid >> 1, ak = (tid & 1) * 16;  // A & P staging: row, r-offset
  const float lcv = lc[(size_t)b * NN + c0 + ar];
  f32x4 acc1[4][4] = {}, acc2[4][4] = {};
  for (int r0 = 0; r0 < NN; r0 += KSTEP) {
    const size_t arow = (size_t)(d0 + ar) * NN + r0 + ak;
    u16x8 a_t0 = *(const u16x8*)&At[arow];
    u16x8 a_t1 = *(const u16x8*)&At[arow + 8];
    u16x8 a_f0 = *(const u16x8*)&Af[arow];
    u16x8 a_f1 = *(const u16x8*)&Af[arow + 8];
    float4 v0 = *(const float4*)&S[(size_t)(c0 + ar) * NN + r0 + ak];
    float4 v1 = *(const float4*)&S[(size_t)(c0 + ar) * NN + r0 + ak + 4];
    float4 v2 = *(const float4*)&S[(size_t)(c0 + ar) * NN + r0 + ak + 8];
    float4 v3 = *(const float4*)&S[(size_t)(c0 + ar) * NN + r0 + ak + 12];
    float4 l0 = *(const float4*)&lr[(size_t)b * NN + r0 + ak];
    float4 l1 = *(const float4*)&lr[(size_t)b * NN + r0 + ak + 4];
    float4 l2 = *(const float4*)&lr[(size_t)b * NN + r0 + ak + 8];
    float4 l3 = *(const float4*)&lr[(size_t)b * NN + r0 + ak + 12];
    float sv[16] = {v0.x, v0.y, v0.z, v0.w, v1.x, v1.y, v1.z, v1.w,
                    v2.x, v2.y, v2.z, v2.w, v3.x, v3.y, v3.z, v3.w};
    float lv[16] = {l0.x, l0.y, l0.z, l0.w, l1.x, l1.y, l1.z, l1.w,
                    l2.x, l2.y, l2.z, l2.w, l3.x, l3.y, l3.z, l3.w};
    u16x8 p1a, p1b, p2a, p2b;
    #pragma unroll
    for (int j = 0; j < 8; ++j) {
      p1a[j] = f2bf_fast(__expf(sv[j] - lcv));
      p2a[j] = f2bf_fast(__expf(sv[j] - lv[j]));
      p1b[j] = f2bf_fast(__expf(sv[j + 8] - lcv));
      p2b[j] = f2bf_fast(__expf(sv[j + 8] - lv[j + 8]));
    }
    __syncthreads();  // prev-iter frag reads done before overwrite
    *(u16x8*)&Ats[ar][ak] = a_t0;
    *(u16x8*)&Ats[ar][ak + 8] = a_t1;
    *(u16x8*)&Afs[ar][ak] = a_f0;
    *(u16x8*)&Afs[ar][ak + 8] = a_f1;
    *(u16x8*)&P1s[ar][ak] = p1a;
    *(u16x8*)&P1s[ar][ak + 8] = p1b;
    *(u16x8*)&P2s[ar][ak] = p2a;
    *(u16x8*)&P2s[ar][ak + 8] = p2b;
    __syncthreads();
    short8 at[4], af[4], b1[4], b2[4];
    #pragma unroll
    for (int mi = 0; mi < 4; ++mi) {
      at[mi] = *(const short8*)&Ats[wd + mi * 16 + fr][fk];
      af[mi] = *(const short8*)&Afs[wd + mi * 16 + fr][fk];
    }
    #pragma unroll
    for (int ci = 0; ci < 4; ++ci) {
      b1[ci] = *(const short8*)&P1s[wcc + ci * 16 + fr][fk];
      b2[ci] = *(const short8*)&P2s[wcc + ci * 16 + fr][fk];
    }
    #pragma unroll
    for (int mi = 0; mi < 4; ++mi)
      #pragma unroll
      for (int ci = 0; ci < 4; ++ci) {
        acc1[mi][ci] = __builtin_amdgcn_mfma_f32_16x16x32_bf16(at[mi], b1[ci], acc1[mi][ci], 0, 0, 0);
        acc2[mi][ci] = __builtin_amdgcn_mfma_f32_16x16x32_bf16(af[mi], b2[ci], acc2[mi][ci], 0, 0, 0);
      }
  }
  float* Ot = out_t + (size_t)b * DD * NN;
  float* Of = out_f + (size_t)b * DD * NN;
  #pragma unroll
  for (int mi = 0; mi < 4; ++mi)
    #pragma unroll
    for (int ci = 0; ci < 4; ++ci)
      #pragma unroll
      for (int q = 0; q < 4; ++q) {
        int d = d0 + wd + mi * 16 + fq + q;
        int c = c0 + wcc + ci * 16 + fr;
        Ot[(size_t)d * NN + c] = acc1[mi][ci][q];
        Of[(size_t)d * NN + c] = acc2[mi][ci][q];
      }
}

// ---------------------------------------------------------------------------
extern "C" void kernel_launch(void* const* d_in, const int* in_sizes, int n_in,
                              void* d_out, int out_size, void* d_ws, size_t ws_size,
                              hipStream_t stream) {
  const float* t = (const float*)d_in[0];
  const float* f = (const float*)d_in[1];
  const float* W = (const float*)d_in[2];
  float* out = (float*)d_out;

  const size_t NE = (size_t)BB * NN * DD;
  char* ws = (char*)d_ws;
  size_t off = 0;
  auto alloc = [&](size_t bytes) { char* p = ws + off; off += (bytes + 255) & ~(size_t)255; return p; };
  // Buffers live past the prologue:
  unsigned short* f_hi = (unsigned short*)alloc(NE * 2);
  unsigned short* f_lo = (unsigned short*)alloc(NE * 2);
  unsigned short* tw_hi = (unsigned short*)alloc(NE * 2);
  unsigned short* tw_lo = (unsigned short*)alloc(NE * 2);
  unsigned short* tT = (unsigned short*)alloc(NE * 2);
  unsigned short* fT = (unsigned short*)alloc(NE * 2);
  unsigned short* Wth = (unsigned short*)alloc((size_t)DD * DD * 2);
  unsigned short* Wtl = (unsigned short*)alloc((size_t)DD * DD * 2);
  float* lr = (float*)alloc((size_t)BB * NN * 4);
  float* lc = (float*)alloc((size_t)BB * NN * 4);
  float2* prow = (float2*)alloc((size_t)BB * NN * 16 * 8);
  float2* pcol = (float2*)alloc((size_t)BB * NN * 16 * 8);
  size_t fixed_bytes = off;
  // sbuf region; t_hi/t_lo ALIAS its start (dead after prologue, stream-ordered).
  float* sbuf = (float*)(ws + fixed_bytes);
  unsigned short* t_hi = (unsigned short*)(ws + fixed_bytes);
  unsigned short* t_lo = t_hi + NE;
  size_t per_batch = (size_t)NN * NN * 4;
  int G = 1;
  if (ws_size > fixed_bytes + per_batch) {
    size_t avail = (ws_size - fixed_bytes) / per_batch;
    G = (int)(avail < BB ? avail : BB);
    if (G < 1) G = 1;
  }

  float* out_t = out;
  float* out_f = out + (size_t)BB * DD * NN;

  // Prologue
  k_split<<<(int)((NE / 4 + 255) / 256), 256, 0, stream>>>(t, t_hi, t_lo, (int)(NE / 4));
  k_split<<<(int)((NE / 4 + 255) / 256), 256, 0, stream>>>(f, f_hi, f_lo, (int)(NE / 4));
  k_splitW<<<DD, DD, 0, stream>>>(W, Wth, Wtl);
  k_transT<<<dim3(NN / 64, DD / 64, BB), 256, 0, stream>>>(t_hi, tT);
  k_transT<<<dim3(NN / 64, DD / 64, BB), 256, 0, stream>>>(f_hi, fT);
  k_gemm_nt<0><<<dim3(256, 2, 1), 256, 0, stream>>>(t_hi, t_lo, Wth, Wtl, tw_hi, tw_lo,
                                                    nullptr, 0);

  for (int b0 = 0; b0 < BB; b0 += G) {
    int g = BB - b0 < G ? BB - b0 : G;
    k_gemm_nt<1><<<dim3(8, 8, g), 256, 0, stream>>>(tw_hi, tw_lo, f_hi, f_lo, nullptr, nullptr,
                                                    sbuf, b0);
    k_stats<<<dim3(16, 16, g), 256, 0, stream>>>(sbuf, prow, pcol);
    k_comb16<<<dim3(NN / 256, g), 256, 0, stream>>>(prow, lr, b0);
    k_comb16<<<dim3(NN / 256, g), 256, 0, stream>>>(pcol, lc, b0);
    k_outdual<<<dim3(NN / 128, DD / 128, g), 256, 0, stream>>>(tT, fT, sbuf, lr, lc,
                                                               out_t, out_f, b0);
  }
}